// Round 14
// baseline (293.650 us; speedup 1.0000x reference)
//
#include <hip/hip_runtime.h>

// SigNet forward, closed-form depth-3 signature + Linear, l-split 2x.
// B=256, L=256, CIN=8, C=9, SIG_CH=819, OUT=128.
//
// Per-l additive form (cross-term folded; x_L read from input directly):
//   s2[i][j]    = sum_l w_i d_j
//   s3[i][j][k] = sum_l [ z_i d_j d_k + w_i d_j * (x_L - X_l)[k] ]
//   w = X - 0.5*D, z = 0.5*X - D/3          (math validated in R13)
//
// Grid 512 = 2 blocks/batch (128 segments each), 1024 threads, plain
// __launch_bounds__(1024) -> VGPR 64, NO spill (R10-proven register shape;
// R13's (704,6) forced VGPR=40 and spilled catastrophically). LDS 37 KB ->
// 2 blocks/CU co-resident = 32 waves/CU main phase. Last-arriving block
// per batch (device atomic, flags zeroed via hipMemsetAsync) combines the
// two ws partials and runs the Linear epilogue.

#define ROWF    132                   // table row stride (33 float4)
#define RANGES  8
#define TPR     81
#define NACT    (RANGES * TPR)        // 648 active threads
#define PSTR    13
#define U1SZ    (NACT * PSTR)         // 8424 floats (tables 3*1188 alias front)
#define WSROW   812                   // floats per ws slot (81 s2 + 729 s3)
#define FLAGOFF (2 * 256 * WSROW)     // float offset of flags
#define NSL     32                    // epilogue W-slices (1024/32)

__global__ __launch_bounds__(1024) void signet_fwd(
    const float* __restrict__ inp,   // [256, 256, 8]
    const float* __restrict__ Wg,    // [819, 128]
    const float* __restrict__ bias,  // [128]
    float* __restrict__ out,         // [256, 128]
    float* __restrict__ wsf,         // ws: 2*256*WSROW floats + 256 flags
    int*   __restrict__ flags)
{
    __shared__ float sig[820];
    __shared__ __align__(16) float u[U1SZ];
    __shared__ int winflag;

    float* Xt = u;                    // [9][132] (dead after main loop)
    float* Dt = u + 9 * ROWF;
    float* Mt = u + 18 * ROWF;        // x_L - X

    const int tid = threadIdx.x;
    const int b   = blockIdx.x >> 1;
    const int h   = blockIdx.x & 1;   // l-half: segments [h*128, h*128+128)

    // ---- prep: tables for this block's 128 segments ----
    if (tid < 256) {
        const int col = tid & 127;
        const int gt  = h * 128 + col;            // global segment index
        const float* rc = inp + (size_t)b * 2048 + (size_t)gt * 8;
        const float* rl = inp + (size_t)b * 2048 + 255 * 8;
        if (tid < 128) {
            float4 c0 = *(const float4*)rc;
            float4 p0 = make_float4(0.f, 0.f, 0.f, 0.f);
            float  tp = 0.f;
            if (gt > 0) { p0 = *(const float4*)(rc - 8); tp = (float)(gt - 1) * (1.0f / 255.0f); }
            float4 xl0 = *(const float4*)rl;
            float cur[5] = { (float)gt * (1.0f / 255.0f), c0.x, c0.y, c0.z, c0.w };
            float prv[5] = { tp, p0.x, p0.y, p0.z, p0.w };
            float xlv[5] = { 1.0f, xl0.x, xl0.y, xl0.z, xl0.w };
            #pragma unroll
            for (int c = 0; c < 5; ++c) {
                Xt[c * ROWF + col] = cur[c];
                Dt[c * ROWF + col] = cur[c] - prv[c];
                Mt[c * ROWF + col] = xlv[c] - cur[c];
            }
        } else {
            float4 c1 = *(const float4*)(rc + 4);
            float4 p1 = make_float4(0.f, 0.f, 0.f, 0.f);
            if (gt > 0) p1 = *(const float4*)(rc - 4);
            float4 xl1 = *(const float4*)(rl + 4);
            float cur[4] = { c1.x, c1.y, c1.z, c1.w };
            float prv[4] = { p1.x, p1.y, p1.z, p1.w };
            float xlv[4] = { xl1.x, xl1.y, xl1.z, xl1.w };
            #pragma unroll
            for (int c = 0; c < 4; ++c) {
                Xt[(5 + c) * ROWF + col] = cur[c];
                Dt[(5 + c) * ROWF + col] = cur[c] - prv[c];
                Mt[(5 + c) * ROWF + col] = xlv[c] - cur[c];
            }
        }
    }
    __syncthreads();

    // ---- main: range rr = tid/81 handles float4 cols [rr*4, rr*4+4) ----
    const bool act = (tid < NACT);
    const int  rr  = tid / TPR;
    const int  lt  = tid - rr * TPR;     // 0..80
    const int  ii  = lt / 9;
    const int  jk  = lt - ii * 9;
    const int  jt  = jk / 3;
    const int  kt  = jk - jt * 3;

    float a[3][3];
    float s2a[3];
    #pragma unroll
    for (int jm = 0; jm < 3; ++jm) {
        s2a[jm] = 0.f;
        a[jm][0] = 0.f; a[jm][1] = 0.f; a[jm][2] = 0.f;
    }

    if (act) {
        const float4* X4 = (const float4*)u;           // [9][33]
        const float4* D4 = X4 + 9 * 33;
        const float4* M4 = X4 + 18 * 33;

        #pragma unroll
        for (int q = 0; q < 4; ++q) {
            const int idx = rr * 4 + q;
            const float4 Xi = X4[ii * 33 + idx];
            const float4 Di = D4[ii * 33 + idx];
            float4 w, z;
            w.x = fmaf(-0.5f, Di.x, Xi.x);
            w.y = fmaf(-0.5f, Di.y, Xi.y);
            w.z = fmaf(-0.5f, Di.z, Xi.z);
            w.w = fmaf(-0.5f, Di.w, Xi.w);
            z.x = fmaf(-(1.0f / 3.0f), Di.x, 0.5f * Xi.x);
            z.y = fmaf(-(1.0f / 3.0f), Di.y, 0.5f * Xi.y);
            z.z = fmaf(-(1.0f / 3.0f), Di.z, 0.5f * Xi.z);
            z.w = fmaf(-(1.0f / 3.0f), Di.w, 0.5f * Xi.w);

            float4 uu[3], vv[3];
            #pragma unroll
            for (int jm = 0; jm < 3; ++jm) {
                const float4 Dj = D4[(3 * jt + jm) * 33 + idx];
                uu[jm].x = w.x * Dj.x;  uu[jm].y = w.y * Dj.y;
                uu[jm].z = w.z * Dj.z;  uu[jm].w = w.w * Dj.w;
                vv[jm].x = z.x * Dj.x;  vv[jm].y = z.y * Dj.y;
                vv[jm].z = z.z * Dj.z;  vv[jm].w = z.w * Dj.w;
                s2a[jm] += (uu[jm].x + uu[jm].y) + (uu[jm].z + uu[jm].w);
            }
            #pragma unroll
            for (int km = 0; km < 3; ++km) {
                const float4 Dk = D4[(3 * kt + km) * 33 + idx];
                const float4 Mk = M4[(3 * kt + km) * 33 + idx];
                #pragma unroll
                for (int jm = 0; jm < 3; ++jm) {
                    a[jm][km] = fmaf(vv[jm].x, Dk.x, fmaf(uu[jm].x, Mk.x, a[jm][km]));
                    a[jm][km] = fmaf(vv[jm].y, Dk.y, fmaf(uu[jm].y, Mk.y, a[jm][km]));
                    a[jm][km] = fmaf(vv[jm].z, Dk.z, fmaf(uu[jm].z, Mk.z, a[jm][km]));
                    a[jm][km] = fmaf(vv[jm].w, Dk.w, fmaf(uu[jm].w, Mk.w, a[jm][km]));
                }
            }
        }
    }
    __syncthreads();   // tables dead; dump may alias

    if (act) {
        float* pa = u + tid * PSTR;
        #pragma unroll
        for (int jm = 0; jm < 3; ++jm) {
            pa[jm * 3 + 0] = a[jm][0];
            pa[jm * 3 + 1] = a[jm][1];
            pa[jm * 3 + 2] = a[jm][2];
        }
        pa[9]  = s2a[0];
        pa[10] = s2a[1];
        pa[11] = s2a[2];
    }
    __syncthreads();

    // ---- block-partial combine -> ws slot ----
    float* slot = wsf + (size_t)(2 * b + h) * WSROW;
    if (tid < 81) {
        const int i2  = tid / 9;
        const int j2  = tid - i2 * 9;
        const int jt2 = j2 / 3;
        const int jm2 = j2 - jt2 * 3;
        const int base = (i2 * 9 + jt2 * 3) * PSTR + 9 + jm2;
        float s = 0.f;
        #pragma unroll
        for (int c = 0; c < RANGES; ++c) s += u[c * TPR * PSTR + base];
        slot[tid] = s;
    }
    if (tid < 729) {
        const int e   = tid;
        const int i3  = e / 81;
        const int rem = e - i3 * 81;
        const int j3  = rem / 9;
        const int k3  = rem - j3 * 9;
        const int jt3 = j3 / 3, jm3 = j3 - jt3 * 3;
        const int kt3 = k3 / 3, km3 = k3 - kt3 * 3;
        const int base = (i3 * 9 + jt3 * 3 + kt3) * PSTR + jm3 * 3 + km3;
        float s = 0.f;
        #pragma unroll
        for (int c = 0; c < RANGES; ++c) s += u[c * TPR * PSTR + base];
        slot[81 + e] = s;
    }

    // ---- last block of this batch combines + epilogue ----
    __threadfence();
    __syncthreads();
    if (tid == 0) winflag = atomicAdd(flags + b, 1);
    __syncthreads();
    if (winflag != 1) return;
    __threadfence();

    const float* s0 = wsf + (size_t)(2 * b) * WSROW;
    const float* s1 = s0 + WSROW;
    if (tid < 9) {
        sig[tid] = (tid == 0) ? 1.0f
                              : inp[(size_t)b * 2048 + 255 * 8 + (tid - 1)];
    }
    if (tid < 81) sig[9 + tid] = s0[tid] + s1[tid];
    if (tid < 729) sig[90 + tid] = s0[81 + tid] + s1[81 + tid];
    __syncthreads();

    // ---- linear: out[b][o] = bias[o] + sum_ch sig[ch]*Wg[ch][o] ----
    {
        const int oq = tid & 31;
        const int sl = tid >> 5;     // 0..31
        float4 acc = make_float4(0.f, 0.f, 0.f, 0.f);
        const float4* Wq = (const float4*)Wg;
        for (int ch = sl; ch < 819; ch += NSL) {
            const float s = sig[ch];
            const float4 wv = Wq[(size_t)ch * 32 + oq];
            acc.x = fmaf(s, wv.x, acc.x);
            acc.y = fmaf(s, wv.y, acc.y);
            acc.z = fmaf(s, wv.z, acc.z);
            acc.w = fmaf(s, wv.w, acc.w);
        }
        float4* pbuf = (float4*)u;               // aliases dead dump region
        pbuf[sl * 32 + oq] = acc;
    }
    __syncthreads();
    if (tid < 32) {
        const float4* pbuf = (const float4*)u;
        float4 r = pbuf[tid];
        #pragma unroll
        for (int s = 1; s < NSL; ++s) {
            const float4 p = pbuf[s * 32 + tid];
            r.x += p.x; r.y += p.y; r.z += p.z; r.w += p.w;
        }
        const float4 bv = ((const float4*)bias)[tid];
        r.x += bv.x; r.y += bv.y; r.z += bv.z; r.w += bv.w;
        ((float4*)(out + (size_t)b * 128))[tid] = r;
    }
}

extern "C" void kernel_launch(void* const* d_in, const int* in_sizes, int n_in,
                              void* d_out, int out_size, void* d_ws, size_t ws_size,
                              hipStream_t stream) {
    const float* inp  = (const float*)d_in[0];
    const float* Wp   = (const float*)d_in[1];
    const float* bias = (const float*)d_in[2];
    float* outp  = (float*)d_out;
    float* wsf   = (float*)d_ws;
    int*   flags = (int*)((char*)d_ws + (size_t)FLAGOFF * 4);
    (void)in_sizes; (void)n_in; (void)out_size; (void)ws_size;

    hipMemsetAsync(flags, 0, 256 * sizeof(int), stream);
    hipLaunchKernelGGL(signet_fwd, dim3(512), dim3(1024), 0, stream,
                       inp, Wp, bias, outp, wsf, flags);
}

// Round 15
// 30.361 us; speedup vs baseline: 9.6721x; 9.6721x over previous
//
#include <hip/hip_runtime.h>

// SigNet forward, closed-form depth-3 signature + Linear, l-split 2x,
// fence-free: partial-y atomicAdd combine (Linear is linear in sig).
// B=256, L=256, CIN=8, C=9, SIG_CH=819, OUT=128.
//
// Per-l additive form (cross-term folded; validated R13/R14):
//   s2[i][j]    = sum_l w_i d_j
//   s3[i][j][k] = sum_l [ z_i d_j d_k + w_i d_j * (x_L - X_l)[k] ]
//   w = X - 0.5*D, z = 0.5*X - D/3
//
// Grid 512 = 2 blocks/batch (128 segments each), 1024 threads,
// __launch_bounds__(1024) (VGPR 64, R10/R14-proven shape). LDS 37 KB ->
// 2 blocks/CU = 32 waves/CU. Each block computes its partial signature,
// multiplies by W, and atomicAdds 128 floats into out (zeroed per call by
// hipMemsetAsync). Exactly 2 float contributions/element -> bit-determinism
// by IEEE commutativity. NO device fences (R14's 293us lesson).

#define ROWF    132                   // table row stride (33 float4)
#define RANGES  8
#define TPR     81
#define NACT    (RANGES * TPR)        // 648 active threads
#define PSTR    13
#define U1SZ    (NACT * PSTR)         // 8424 floats (tables 3*1188 alias front)
#define NSL     32                    // epilogue W-slices (1024/32)

__global__ __launch_bounds__(1024) void signet_fwd(
    const float* __restrict__ inp,   // [256, 256, 8]
    const float* __restrict__ Wg,    // [819, 128]
    const float* __restrict__ bias,  // [128]
    float* __restrict__ out)         // [256, 128], pre-zeroed per call
{
    __shared__ float sig[820];
    __shared__ __align__(16) float u[U1SZ];

    float* Xt = u;                    // [9][132] (dead after main loop)
    float* Dt = u + 9 * ROWF;
    float* Mt = u + 18 * ROWF;        // x_L - X

    const int tid = threadIdx.x;
    const int b   = blockIdx.x >> 1;
    const int h   = blockIdx.x & 1;   // l-half: segments [h*128, h*128+128)

    // ---- prep: tables for this block's 128 segments ----
    if (tid < 256) {
        const int col = tid & 127;
        const int gt  = h * 128 + col;            // global segment index
        const float* rc = inp + (size_t)b * 2048 + (size_t)gt * 8;
        const float* rl = inp + (size_t)b * 2048 + 255 * 8;
        if (tid < 128) {
            float4 c0 = *(const float4*)rc;
            float4 p0 = make_float4(0.f, 0.f, 0.f, 0.f);
            float  tp = 0.f;
            if (gt > 0) { p0 = *(const float4*)(rc - 8); tp = (float)(gt - 1) * (1.0f / 255.0f); }
            float4 xl0 = *(const float4*)rl;
            float cur[5] = { (float)gt * (1.0f / 255.0f), c0.x, c0.y, c0.z, c0.w };
            float prv[5] = { tp, p0.x, p0.y, p0.z, p0.w };
            float xlv[5] = { 1.0f, xl0.x, xl0.y, xl0.z, xl0.w };
            #pragma unroll
            for (int c = 0; c < 5; ++c) {
                Xt[c * ROWF + col] = cur[c];
                Dt[c * ROWF + col] = cur[c] - prv[c];
                Mt[c * ROWF + col] = xlv[c] - cur[c];
            }
        } else {
            float4 c1 = *(const float4*)(rc + 4);
            float4 p1 = make_float4(0.f, 0.f, 0.f, 0.f);
            if (gt > 0) p1 = *(const float4*)(rc - 4);
            float4 xl1 = *(const float4*)(rl + 4);
            float cur[4] = { c1.x, c1.y, c1.z, c1.w };
            float prv[4] = { p1.x, p1.y, p1.z, p1.w };
            float xlv[4] = { xl1.x, xl1.y, xl1.z, xl1.w };
            #pragma unroll
            for (int c = 0; c < 4; ++c) {
                Xt[(5 + c) * ROWF + col] = cur[c];
                Dt[(5 + c) * ROWF + col] = cur[c] - prv[c];
                Mt[(5 + c) * ROWF + col] = xlv[c] - cur[c];
            }
        }
    }
    __syncthreads();

    // ---- main: range rr = tid/81 handles float4 cols [rr*4, rr*4+4) ----
    const bool act = (tid < NACT);
    const int  rr  = tid / TPR;
    const int  lt  = tid - rr * TPR;     // 0..80
    const int  ii  = lt / 9;
    const int  jk  = lt - ii * 9;
    const int  jt  = jk / 3;
    const int  kt  = jk - jt * 3;

    float a[3][3];
    float s2a[3];
    #pragma unroll
    for (int jm = 0; jm < 3; ++jm) {
        s2a[jm] = 0.f;
        a[jm][0] = 0.f; a[jm][1] = 0.f; a[jm][2] = 0.f;
    }

    if (act) {
        const float4* X4 = (const float4*)u;           // [9][33]
        const float4* D4 = X4 + 9 * 33;
        const float4* M4 = X4 + 18 * 33;

        #pragma unroll
        for (int q = 0; q < 4; ++q) {
            const int idx = rr * 4 + q;
            const float4 Xi = X4[ii * 33 + idx];
            const float4 Di = D4[ii * 33 + idx];
            float4 w, z;
            w.x = fmaf(-0.5f, Di.x, Xi.x);
            w.y = fmaf(-0.5f, Di.y, Xi.y);
            w.z = fmaf(-0.5f, Di.z, Xi.z);
            w.w = fmaf(-0.5f, Di.w, Xi.w);
            z.x = fmaf(-(1.0f / 3.0f), Di.x, 0.5f * Xi.x);
            z.y = fmaf(-(1.0f / 3.0f), Di.y, 0.5f * Xi.y);
            z.z = fmaf(-(1.0f / 3.0f), Di.z, 0.5f * Xi.z);
            z.w = fmaf(-(1.0f / 3.0f), Di.w, 0.5f * Xi.w);

            float4 uu[3], vv[3];
            #pragma unroll
            for (int jm = 0; jm < 3; ++jm) {
                const float4 Dj = D4[(3 * jt + jm) * 33 + idx];
                uu[jm].x = w.x * Dj.x;  uu[jm].y = w.y * Dj.y;
                uu[jm].z = w.z * Dj.z;  uu[jm].w = w.w * Dj.w;
                vv[jm].x = z.x * Dj.x;  vv[jm].y = z.y * Dj.y;
                vv[jm].z = z.z * Dj.z;  vv[jm].w = z.w * Dj.w;
                s2a[jm] += (uu[jm].x + uu[jm].y) + (uu[jm].z + uu[jm].w);
            }
            #pragma unroll
            for (int km = 0; km < 3; ++km) {
                const float4 Dk = D4[(3 * kt + km) * 33 + idx];
                const float4 Mk = M4[(3 * kt + km) * 33 + idx];
                #pragma unroll
                for (int jm = 0; jm < 3; ++jm) {
                    a[jm][km] = fmaf(vv[jm].x, Dk.x, fmaf(uu[jm].x, Mk.x, a[jm][km]));
                    a[jm][km] = fmaf(vv[jm].y, Dk.y, fmaf(uu[jm].y, Mk.y, a[jm][km]));
                    a[jm][km] = fmaf(vv[jm].z, Dk.z, fmaf(uu[jm].z, Mk.z, a[jm][km]));
                    a[jm][km] = fmaf(vv[jm].w, Dk.w, fmaf(uu[jm].w, Mk.w, a[jm][km]));
                }
            }
        }
    }
    __syncthreads();   // tables dead; dump may alias

    if (act) {
        float* pa = u + tid * PSTR;
        #pragma unroll
        for (int jm = 0; jm < 3; ++jm) {
            pa[jm * 3 + 0] = a[jm][0];
            pa[jm * 3 + 1] = a[jm][1];
            pa[jm * 3 + 2] = a[jm][2];
        }
        pa[9]  = s2a[0];
        pa[10] = s2a[1];
        pa[11] = s2a[2];
    }
    __syncthreads();

    // ---- combine -> partial sig (this l-half only) ----
    if (tid < 9) {
        sig[tid] = (h == 0)
            ? ((tid == 0) ? 1.0f : inp[(size_t)b * 2048 + 255 * 8 + (tid - 1)])
            : 0.0f;
    }
    if (tid < 81) {
        const int i2  = tid / 9;
        const int j2  = tid - i2 * 9;
        const int jt2 = j2 / 3;
        const int jm2 = j2 - jt2 * 3;
        const int base = (i2 * 9 + jt2 * 3) * PSTR + 9 + jm2;
        float s = 0.f;
        #pragma unroll
        for (int c = 0; c < RANGES; ++c) s += u[c * TPR * PSTR + base];
        sig[9 + tid] = s;
    }
    if (tid < 729) {
        const int e   = tid;
        const int i3  = e / 81;
        const int rem = e - i3 * 81;
        const int j3  = rem / 9;
        const int k3  = rem - j3 * 9;
        const int jt3 = j3 / 3, jm3 = j3 - jt3 * 3;
        const int kt3 = k3 / 3, km3 = k3 - kt3 * 3;
        const int base = (i3 * 9 + jt3 * 3 + kt3) * PSTR + jm3 * 3 + km3;
        float s = 0.f;
        #pragma unroll
        for (int c = 0; c < RANGES; ++c) s += u[c * TPR * PSTR + base];
        sig[90 + e] = s;
    }
    __syncthreads();

    // ---- partial linear: y_h[o] = sum_ch sig_h[ch]*Wg[ch][o] (+bias @h==0) ----
    {
        const int oq = tid & 31;
        const int sl = tid >> 5;     // 0..31
        float4 acc = make_float4(0.f, 0.f, 0.f, 0.f);
        const float4* Wq = (const float4*)Wg;
        for (int ch = sl; ch < 819; ch += NSL) {
            const float s = sig[ch];
            const float4 wv = Wq[(size_t)ch * 32 + oq];
            acc.x = fmaf(s, wv.x, acc.x);
            acc.y = fmaf(s, wv.y, acc.y);
            acc.z = fmaf(s, wv.z, acc.z);
            acc.w = fmaf(s, wv.w, acc.w);
        }
        float4* pbuf = (float4*)u;               // aliases dead dump region
        pbuf[sl * 32 + oq] = acc;
    }
    __syncthreads();
    if (tid < 32) {
        const float4* pbuf = (const float4*)u;
        float4 r = pbuf[tid];
        #pragma unroll
        for (int s = 1; s < NSL; ++s) {
            const float4 p = pbuf[s * 32 + tid];
            r.x += p.x; r.y += p.y; r.z += p.z; r.w += p.w;
        }
        if (h == 0) {
            const float4 bv = ((const float4*)bias)[tid];
            r.x += bv.x; r.y += bv.y; r.z += bv.z; r.w += bv.w;
        }
        float* dst = out + (size_t)b * 128 + tid * 4;
        atomicAdd(dst + 0, r.x);
        atomicAdd(dst + 1, r.y);
        atomicAdd(dst + 2, r.z);
        atomicAdd(dst + 3, r.w);
    }
}

extern "C" void kernel_launch(void* const* d_in, const int* in_sizes, int n_in,
                              void* d_out, int out_size, void* d_ws, size_t ws_size,
                              hipStream_t stream) {
    const float* inp  = (const float*)d_in[0];
    const float* Wp   = (const float*)d_in[1];
    const float* bias = (const float*)d_in[2];
    float* outp = (float*)d_out;
    (void)in_sizes; (void)n_in; (void)d_ws; (void)ws_size;

    hipMemsetAsync(outp, 0, (size_t)out_size * sizeof(float), stream);
    hipLaunchKernelGGL(signet_fwd, dim3(512), dim3(1024), 0, stream,
                       inp, Wp, bias, outp);
}

// Round 16
// 22.512 us; speedup vs baseline: 13.0441x; 1.3486x over previous
//
#include <hip/hip_runtime.h>

// SigNet forward, closed-form depth-3 signature + Linear, 2-kernel split.
// B=256, L=256, CIN=8, C=9, SIG_CH=819, OUT=128.
//
// Per-l additive form (cross-term folded; validated R13-R15):
//   s2[i][j]    = sum_l w_i d_j
//   s3[i][j][k] = sum_l [ z_i d_j d_k + w_i d_j * (x_L - X_l)[k] ]
//   w = X - 0.5*D, z = 0.5*X - D/3
//
// Kernel A (signature): grid 512 = 2 blocks/batch (128 segments each),
// 1024 threads, 12-acc/thread (VGPR 64, no spill - R10/R14 shape), ~34 KB
// LDS -> 2 blocks/CU = 24 waves/CU. Writes partial (s2,s3') to ws.
// Kernel B (linear): grid 512 = 2 blocks/batch (64 outputs each), combines
// the two ws halves (stream ordering replaces fences - R5-proven) + GEMV.

#define ROWF    132                   // table row stride (33 float4)
#define RANGES  8
#define TPR     81
#define NACT    (RANGES * TPR)        // 648 active threads
#define PSTR    13
#define U1SZ    (NACT * PSTR)         // 8424 floats (tables 3*1188 alias front)
#define WSROW   812                   // floats per ws slot (81 s2 + 729 s3)

__global__ __launch_bounds__(1024) void signet_part(
    const float* __restrict__ inp,   // [256, 256, 8]
    float* __restrict__ wsf)         // [512][WSROW]
{
    __shared__ __align__(16) float u[U1SZ];

    float* Xt = u;                    // [9][132] (dead after main loop)
    float* Dt = u + 9 * ROWF;
    float* Mt = u + 18 * ROWF;        // x_L - X

    const int tid = threadIdx.x;
    const int b   = blockIdx.x >> 1;
    const int h   = blockIdx.x & 1;   // l-half: segments [h*128, h*128+128)

    // ---- prep: tables for this block's 128 segments ----
    if (tid < 256) {
        const int col = tid & 127;
        const int gt  = h * 128 + col;            // global segment index
        const float* rc = inp + (size_t)b * 2048 + (size_t)gt * 8;
        const float* rl = inp + (size_t)b * 2048 + 255 * 8;
        if (tid < 128) {
            float4 c0 = *(const float4*)rc;
            float4 p0 = make_float4(0.f, 0.f, 0.f, 0.f);
            float  tp = 0.f;
            if (gt > 0) { p0 = *(const float4*)(rc - 8); tp = (float)(gt - 1) * (1.0f / 255.0f); }
            float4 xl0 = *(const float4*)rl;
            float cur[5] = { (float)gt * (1.0f / 255.0f), c0.x, c0.y, c0.z, c0.w };
            float prv[5] = { tp, p0.x, p0.y, p0.z, p0.w };
            float xlv[5] = { 1.0f, xl0.x, xl0.y, xl0.z, xl0.w };
            #pragma unroll
            for (int c = 0; c < 5; ++c) {
                Xt[c * ROWF + col] = cur[c];
                Dt[c * ROWF + col] = cur[c] - prv[c];
                Mt[c * ROWF + col] = xlv[c] - cur[c];
            }
        } else {
            float4 c1 = *(const float4*)(rc + 4);
            float4 p1 = make_float4(0.f, 0.f, 0.f, 0.f);
            if (gt > 0) p1 = *(const float4*)(rc - 4);
            float4 xl1 = *(const float4*)(rl + 4);
            float cur[4] = { c1.x, c1.y, c1.z, c1.w };
            float prv[4] = { p1.x, p1.y, p1.z, p1.w };
            float xlv[4] = { xl1.x, xl1.y, xl1.z, xl1.w };
            #pragma unroll
            for (int c = 0; c < 4; ++c) {
                Xt[(5 + c) * ROWF + col] = cur[c];
                Dt[(5 + c) * ROWF + col] = cur[c] - prv[c];
                Mt[(5 + c) * ROWF + col] = xlv[c] - cur[c];
            }
        }
    }
    __syncthreads();

    // ---- main: range rr = tid/81 handles float4 cols [rr*4, rr*4+4) ----
    const bool act = (tid < NACT);
    const int  rr  = tid / TPR;
    const int  lt  = tid - rr * TPR;     // 0..80
    const int  ii  = lt / 9;
    const int  jk  = lt - ii * 9;
    const int  jt  = jk / 3;
    const int  kt  = jk - jt * 3;

    float a[3][3];
    float s2a[3];
    #pragma unroll
    for (int jm = 0; jm < 3; ++jm) {
        s2a[jm] = 0.f;
        a[jm][0] = 0.f; a[jm][1] = 0.f; a[jm][2] = 0.f;
    }

    if (act) {
        const float4* X4 = (const float4*)u;           // [9][33]
        const float4* D4 = X4 + 9 * 33;
        const float4* M4 = X4 + 18 * 33;

        #pragma unroll
        for (int q = 0; q < 4; ++q) {
            const int idx = rr * 4 + q;
            const float4 Xi = X4[ii * 33 + idx];
            const float4 Di = D4[ii * 33 + idx];
            float4 w, z;
            w.x = fmaf(-0.5f, Di.x, Xi.x);
            w.y = fmaf(-0.5f, Di.y, Xi.y);
            w.z = fmaf(-0.5f, Di.z, Xi.z);
            w.w = fmaf(-0.5f, Di.w, Xi.w);
            z.x = fmaf(-(1.0f / 3.0f), Di.x, 0.5f * Xi.x);
            z.y = fmaf(-(1.0f / 3.0f), Di.y, 0.5f * Xi.y);
            z.z = fmaf(-(1.0f / 3.0f), Di.z, 0.5f * Xi.z);
            z.w = fmaf(-(1.0f / 3.0f), Di.w, 0.5f * Xi.w);

            float4 uu[3], vv[3];
            #pragma unroll
            for (int jm = 0; jm < 3; ++jm) {
                const float4 Dj = D4[(3 * jt + jm) * 33 + idx];
                uu[jm].x = w.x * Dj.x;  uu[jm].y = w.y * Dj.y;
                uu[jm].z = w.z * Dj.z;  uu[jm].w = w.w * Dj.w;
                vv[jm].x = z.x * Dj.x;  vv[jm].y = z.y * Dj.y;
                vv[jm].z = z.z * Dj.z;  vv[jm].w = z.w * Dj.w;
                s2a[jm] += (uu[jm].x + uu[jm].y) + (uu[jm].z + uu[jm].w);
            }
            #pragma unroll
            for (int km = 0; km < 3; ++km) {
                const float4 Dk = D4[(3 * kt + km) * 33 + idx];
                const float4 Mk = M4[(3 * kt + km) * 33 + idx];
                #pragma unroll
                for (int jm = 0; jm < 3; ++jm) {
                    a[jm][km] = fmaf(vv[jm].x, Dk.x, fmaf(uu[jm].x, Mk.x, a[jm][km]));
                    a[jm][km] = fmaf(vv[jm].y, Dk.y, fmaf(uu[jm].y, Mk.y, a[jm][km]));
                    a[jm][km] = fmaf(vv[jm].z, Dk.z, fmaf(uu[jm].z, Mk.z, a[jm][km]));
                    a[jm][km] = fmaf(vv[jm].w, Dk.w, fmaf(uu[jm].w, Mk.w, a[jm][km]));
                }
            }
        }
    }
    __syncthreads();   // tables dead; dump may alias

    if (act) {
        float* pa = u + tid * PSTR;
        #pragma unroll
        for (int jm = 0; jm < 3; ++jm) {
            pa[jm * 3 + 0] = a[jm][0];
            pa[jm * 3 + 1] = a[jm][1];
            pa[jm * 3 + 2] = a[jm][2];
        }
        pa[9]  = s2a[0];
        pa[10] = s2a[1];
        pa[11] = s2a[2];
    }
    __syncthreads();

    // ---- combine -> ws slot (partial s2[81], s3'[729] for this l-half) ----
    float* slot = wsf + (size_t)(2 * b + h) * WSROW;
    if (tid < 81) {
        const int i2  = tid / 9;
        const int j2  = tid - i2 * 9;
        const int jt2 = j2 / 3;
        const int jm2 = j2 - jt2 * 3;
        const int base = (i2 * 9 + jt2 * 3) * PSTR + 9 + jm2;
        float s = 0.f;
        #pragma unroll
        for (int c = 0; c < RANGES; ++c) s += u[c * TPR * PSTR + base];
        slot[tid] = s;
    }
    if (tid < 729) {
        const int e   = tid;
        const int i3  = e / 81;
        const int rem = e - i3 * 81;
        const int j3  = rem / 9;
        const int k3  = rem - j3 * 9;
        const int jt3 = j3 / 3, jm3 = j3 - jt3 * 3;
        const int kt3 = k3 / 3, km3 = k3 - kt3 * 3;
        const int base = (i3 * 9 + jt3 * 3 + kt3) * PSTR + jm3 * 3 + km3;
        float s = 0.f;
        #pragma unroll
        for (int c = 0; c < RANGES; ++c) s += u[c * TPR * PSTR + base];
        slot[81 + e] = s;
    }
}

__global__ __launch_bounds__(512) void signet_fin(
    const float* __restrict__ inp,   // [256, 256, 8]
    const float* __restrict__ ws,    // [512][WSROW]
    const float* __restrict__ Wg,    // [819, 128]
    const float* __restrict__ bias,  // [128]
    float* __restrict__ out)         // [256, 128]
{
    __shared__ float sig[820];
    __shared__ __align__(16) float4 pbuf[32][16];

    const int tid = threadIdx.x;
    const int b   = blockIdx.x >> 1;
    const int h   = blockIdx.x & 1;       // output half: cols [h*64, h*64+64)

    const float* s0 = ws + (size_t)(2 * b) * WSROW;
    const float* s1 = s0 + WSROW;

    if (tid < 81) sig[9 + tid] = s0[tid] + s1[tid];
    if (tid < 9)  sig[tid] = (tid == 0) ? 1.0f
                             : inp[(size_t)b * 2048 + 255 * 8 + (tid - 1)];
    for (int e = tid; e < 729; e += 512) {
        sig[90 + e] = s0[81 + e] + s1[81 + e];   // cross-term already folded
    }
    __syncthreads();

    // ---- linear over output half h ----
    {
        const int oq = tid & 15;     // float4 within half
        const int sl = tid >> 4;     // channel slice 0..31
        const int cb = h * 16 + oq;  // float4 col in full row
        float4 acc = make_float4(0.f, 0.f, 0.f, 0.f);
        const float4* Wq = (const float4*)Wg;
        for (int ch = sl; ch < 819; ch += 32) {
            const float s = sig[ch];
            const float4 wv = Wq[(size_t)ch * 32 + cb];
            acc.x = fmaf(s, wv.x, acc.x);
            acc.y = fmaf(s, wv.y, acc.y);
            acc.z = fmaf(s, wv.z, acc.z);
            acc.w = fmaf(s, wv.w, acc.w);
        }
        pbuf[sl][oq] = acc;
    }
    __syncthreads();
    if (tid < 16) {
        float4 r = pbuf[0][tid];
        #pragma unroll
        for (int s = 1; s < 32; ++s) {
            const float4 p = pbuf[s][tid];
            r.x += p.x; r.y += p.y; r.z += p.z; r.w += p.w;
        }
        const float4 bv = ((const float4*)bias)[h * 16 + tid];
        r.x += bv.x; r.y += bv.y; r.z += bv.z; r.w += bv.w;
        ((float4*)(out + (size_t)b * 128 + h * 64))[tid] = r;
    }
}

extern "C" void kernel_launch(void* const* d_in, const int* in_sizes, int n_in,
                              void* d_out, int out_size, void* d_ws, size_t ws_size,
                              hipStream_t stream) {
    const float* inp  = (const float*)d_in[0];
    const float* Wp   = (const float*)d_in[1];
    const float* bias = (const float*)d_in[2];
    float* outp = (float*)d_out;
    float* wsf  = (float*)d_ws;
    (void)in_sizes; (void)n_in; (void)out_size; (void)ws_size;

    hipLaunchKernelGGL(signet_part, dim3(512), dim3(1024), 0, stream, inp, wsf);
    hipLaunchKernelGGL(signet_fin,  dim3(512), dim3(512),  0, stream,
                       inp, wsf, Wp, bias, outp);
}